// Round 7
// baseline (3178.455 us; speedup 1.0000x reference)
//
#include <hip/hip_runtime.h>
#include <hip/hip_bf16.h>

#define NV 32000
#define NE 512
#define NH 512
#define NB 16
#define NT 128
#define NS 128

// ---------------- workspace layout (bytes) ----------------
static constexpr size_t CNT_OFF  = 0;                                    // 1024 uints
static constexpr size_t WHHT_OFF = 4096;                                 // [512][1536] f32
static constexpr size_t GI_OFF   = WHHT_OFF + (size_t)3*NH*NH*4;         // [T][B][1536] f32
static constexpr size_t HALL_OFF = GI_OFF + (size_t)NT*NB*3*NH*4;        // [T+1][B][512] f32
static constexpr size_t COMB_OFF = HALL_OFF + (size_t)(NT+1)*NB*NH*4;    // [B*T][1024] f32
static constexpr size_t ATT_OFF  = COMB_OFF + (size_t)NB*NT*2*NH*4;      // [B*T][512] f32 (attended)
static constexpr size_t WS_NEED  = ATT_OFF + (size_t)NB*NT*NH*4;         // ~33 MB

// ---------------- K1: prep (w_hh transpose, h0 copy, counters) ----------------
__global__ __launch_bounds__(256) void k_prep(const float* __restrict__ w_hh,
                                              const float* __restrict__ dh,
                                              float* __restrict__ whhT,
                                              float* __restrict__ h_all,
                                              unsigned int* __restrict__ cnt) {
  long long i0 = (long long)blockIdx.x * blockDim.x + threadIdx.x;
  long long stride = (long long)gridDim.x * blockDim.x;
  // w_hh [1536][512] -> whhT [512][1536]
  for (long long i = i0; i < (long long)3 * NH * NH; i += stride) {
    int k = (int)(i / (3 * NH)), j = (int)(i % (3 * NH));
    whhT[i] = w_hh[(long long)j * NH + k];
  }
  // h_all[0] = decoder_hidden
  for (long long i = i0; i < NB * NH; i += stride) h_all[i] = dh[i];
  // barrier counters
  for (long long i = i0; i < 1024; i += stride) cnt[i] = 0u;
}

// ---------------- K2: gi = emb(text_vec) @ w_ih^T + b_ih  (fp32, 64x64 tile) ----------------
__global__ __launch_bounds__(256) void k_gi(const int* __restrict__ tv,
                                            const float* __restrict__ emb,
                                            const float* __restrict__ w_ih,
                                            const float* __restrict__ b_ih,
                                            float* __restrict__ gi_all) {
  __shared__ float As[16][64];
  __shared__ float Bs[16][64];
  const int tid = threadIdx.x;
  const int n0 = blockIdx.x * 64;   // j (0..1535)
  const int m0 = blockIdx.y * 64;   // bt row (0..2047)
  float acc[4][4] = {};
  const int rl = tid >> 2;          // 0..63
  const int kq = (tid & 3) * 4;     // 0,4,8,12
  const int tvr = tv[m0 + rl];
  const float* arow = emb + (long long)tvr * NE;
  const int tm = tid & 15, tn = tid >> 4;
  for (int k0 = 0; k0 < NE; k0 += 16) {
    __syncthreads();
    float4 av = make_float4(0.f, 0.f, 0.f, 0.f);
    if (tvr != 0) av = *(const float4*)(arow + k0 + kq);
    float4 bv = *(const float4*)(w_ih + (long long)(n0 + rl) * NE + k0 + kq);
    As[kq + 0][rl] = av.x; As[kq + 1][rl] = av.y; As[kq + 2][rl] = av.z; As[kq + 3][rl] = av.w;
    Bs[kq + 0][rl] = bv.x; Bs[kq + 1][rl] = bv.y; Bs[kq + 2][rl] = bv.z; Bs[kq + 3][rl] = bv.w;
    __syncthreads();
#pragma unroll
    for (int kk = 0; kk < 16; ++kk) {
      float4 a = *(const float4*)&As[kk][tm * 4];
      float4 b = *(const float4*)&Bs[kk][tn * 4];
      float ar[4] = {a.x, a.y, a.z, a.w}, br[4] = {b.x, b.y, b.z, b.w};
#pragma unroll
      for (int i = 0; i < 4; ++i)
#pragma unroll
        for (int j = 0; j < 4; ++j) acc[i][j] = fmaf(ar[i], br[j], acc[i][j]);
    }
  }
#pragma unroll
  for (int i = 0; i < 4; ++i) {
    int r = m0 + tm * 4 + i;                 // r = b*128 + t
    long long gb = (long long)((r & 127) * 16 + (r >> 7)) * (3 * NH);  // (t*16+b)*1536
#pragma unroll
    for (int j = 0; j < 4; ++j) {
      int jg = n0 + tn * 4 + j;
      gi_all[gb + jg] = acc[i][j] + b_ih[jg];
    }
  }
}

// ---------------- K3: GRU recurrence. 64 blocks = 16 b x 4 h-slices ----------------
__global__ __launch_bounds__(256) void k_rec(const float* __restrict__ whhT,
                                             const float* __restrict__ gi_all,
                                             const float* __restrict__ b_hh,
                                             float* __restrict__ h_all,
                                             unsigned int* __restrict__ cnt,
                                             float* __restrict__ d_hf) {
  const int tid = threadIdx.x;
  const int b = blockIdx.x & 15, sub = blockIdx.x >> 4;
  const int hl = tid & 127, kc = tid >> 7;   // 128 h x 2 k-halves
  const int h = sub * 128 + hl;
  __shared__ float hbuf[512];
  __shared__ float part[3][128];
  const float bhr = b_hh[h], bhz = b_hh[512 + h], bhn = b_hh[1024 + h];
  unsigned int* flag = &cnt[b * 64];
  for (int t = 0; t < NT; ++t) {
    float* hsrc = h_all + (long long)(t * 16 + b) * 512;
    hbuf[tid] = __hip_atomic_load(hsrc + tid, __ATOMIC_RELAXED, __HIP_MEMORY_SCOPE_AGENT);
    hbuf[tid + 256] = __hip_atomic_load(hsrc + tid + 256, __ATOMIC_RELAXED, __HIP_MEMORY_SCOPE_AGENT);
    __syncthreads();
    float ar = 0.f, az = 0.f, an = 0.f;
    const int kbase = kc * 256;
#pragma unroll 4
    for (int k = 0; k < 256; ++k) {
      float hk = hbuf[kbase + k];
      const float* wr = whhT + (long long)(kbase + k) * 1536;
      ar = fmaf(hk, wr[h], ar);
      az = fmaf(hk, wr[512 + h], az);
      an = fmaf(hk, wr[1024 + h], an);
    }
    if (kc) { part[0][hl] = ar; part[1][hl] = az; part[2][hl] = an; }
    __syncthreads();
    if (!kc) {
      ar += part[0][hl] + bhr;
      az += part[1][hl] + bhz;
      an += part[2][hl] + bhn;
      const float* gi = gi_all + (long long)(t * 16 + b) * 1536;
      float r = 1.f / (1.f + expf(-(gi[h] + ar)));
      float z = 1.f / (1.f + expf(-(gi[512 + h] + az)));
      float n = tanhf(gi[1024 + h] + r * an);
      float hp = hbuf[h];
      float hv = (1.f - z) * n + z * hp;
      __hip_atomic_store(&h_all[(long long)((t + 1) * 16 + b) * 512 + h], hv,
                         __ATOMIC_RELAXED, __HIP_MEMORY_SCOPE_AGENT);
      if (t == NT - 1) d_hf[b * 512 + h] = hv;
    }
    __syncthreads();
    if (t < NT - 1) {
      if (tid == 0) {
        __hip_atomic_fetch_add(flag, 1u, __ATOMIC_RELEASE, __HIP_MEMORY_SCOPE_AGENT);
        unsigned int target = 4u * (unsigned)(t + 1);
        int g = 0;
        while (__hip_atomic_load(flag, __ATOMIC_ACQUIRE, __HIP_MEMORY_SCOPE_AGENT) < target &&
               ++g < (1 << 22)) {}
      }
      __syncthreads();
    }
  }
}

// ---------------- K4: attention per (t,b): scores->softmax->mix, build combined ----------------
__global__ __launch_bounds__(256) void k_attn(const float* __restrict__ h_all,
                                              const float* __restrict__ enc,
                                              const int* __restrict__ mask,
                                              float* __restrict__ d_attn,
                                              float* __restrict__ comb) {
  const int g = blockIdx.x;
  const int t = g >> 4, b = g & 15;
  const int tid = threadIdx.x;
  __shared__ float hb[512];
  __shared__ float red[256];
  __shared__ float wb[128];
  __shared__ float smax, ssum;
  const float* hsrc = h_all + (long long)((t + 1) * 16 + b) * 512;
  hb[tid] = hsrc[tid];
  hb[tid + 256] = hsrc[tid + 256];
  __syncthreads();
  const int s = tid & 127, half = tid >> 7;
  const float* erow = enc + (long long)(b * 128 + s) * 512 + half * 256;
  float p = 0.f;
#pragma unroll 8
  for (int k = 0; k < 256; ++k) p = fmaf(hb[half * 256 + k], erow[k], p);
  red[tid] = p;
  __syncthreads();
  float sc = 0.f;
  if (tid < 128) {
    sc = red[tid] + red[tid + 128];
    if (mask[b * 128 + tid] == 0) sc = -1e6f;
    wb[tid] = sc;
  }
  __syncthreads();
  if (tid < 64) {
    float m2 = fmaxf(wb[tid], wb[tid + 64]);
    for (int off = 32; off; off >>= 1) m2 = fmaxf(m2, __shfl_down(m2, off));
    if (tid == 0) smax = m2;
  }
  __syncthreads();
  if (tid < 128) wb[tid] = expf(sc - smax);
  __syncthreads();
  if (tid < 64) {
    float s2 = wb[tid] + wb[tid + 64];
    for (int off = 32; off; off >>= 1) s2 += __shfl_down(s2, off);
    if (tid == 0) ssum = s2;
  }
  __syncthreads();
  float inv = 1.f / ssum;
  if (tid < 128) {
    float w = wb[tid] * inv;
    wb[tid] = w;
    d_attn[(long long)(t * 16 + b) * 128 + tid] = w;
  }
  __syncthreads();
  long long crow = (long long)(b * 128 + t) * 1024;
  for (int hh = tid; hh < 512; hh += 256) {
    float acc = 0.f;
#pragma unroll 8
    for (int s2 = 0; s2 < 128; ++s2) acc = fmaf(wb[s2], enc[(long long)(b * 128 + s2) * 512 + hh], acc);
    comb[crow + 512 + hh] = acc;
  }
  comb[crow + tid] = hb[tid];
  comb[crow + tid + 256] = hb[tid + 256];
}

// ---------------- K5: attended = tanh(combined @ lin_out_w^T) -> f32 ----------------
__global__ __launch_bounds__(256) void k_att_lin(const float* __restrict__ comb,
                                                 const float* __restrict__ W,
                                                 float* __restrict__ attout) {
  __shared__ float As[16][64];
  __shared__ float Bs[16][64];
  const int tid = threadIdx.x;
  const int n0 = blockIdx.x * 64;   // o (0..511)
  const int m0 = blockIdx.y * 64;   // r (0..2047)
  float acc[4][4] = {};
  const int rl = tid >> 2;
  const int kq = (tid & 3) * 4;
  const int tm = tid & 15, tn = tid >> 4;
  for (int k0 = 0; k0 < 1024; k0 += 16) {
    __syncthreads();
    float4 av = *(const float4*)(comb + (long long)(m0 + rl) * 1024 + k0 + kq);
    float4 bv = *(const float4*)(W + (long long)(n0 + rl) * 1024 + k0 + kq);
    As[kq + 0][rl] = av.x; As[kq + 1][rl] = av.y; As[kq + 2][rl] = av.z; As[kq + 3][rl] = av.w;
    Bs[kq + 0][rl] = bv.x; Bs[kq + 1][rl] = bv.y; Bs[kq + 2][rl] = bv.z; Bs[kq + 3][rl] = bv.w;
    __syncthreads();
#pragma unroll
    for (int kk = 0; kk < 16; ++kk) {
      float4 a = *(const float4*)&As[kk][tm * 4];
      float4 b = *(const float4*)&Bs[kk][tn * 4];
      float ar[4] = {a.x, a.y, a.z, a.w}, br[4] = {b.x, b.y, b.z, b.w};
#pragma unroll
      for (int i = 0; i < 4; ++i)
#pragma unroll
        for (int j = 0; j < 4; ++j) acc[i][j] = fmaf(ar[i], br[j], acc[i][j]);
    }
  }
#pragma unroll
  for (int i = 0; i < 4; ++i) {
    int r = m0 + tm * 4 + i;
#pragma unroll
    for (int j = 0; j < 4; ++j) {
      int o = n0 + tn * 4 + j;
      attout[(long long)r * 512 + o] = tanhf(acc[i][j]);
    }
  }
}

// ---------------- K6: scores = attended @ out_w^T + out_b, plain fp32, f32 out ----------------
__global__ __launch_bounds__(256) void k_out32(const float* __restrict__ A,
                                               const float* __restrict__ Bw,
                                               const float* __restrict__ bias,
                                               float* __restrict__ C) {
  __shared__ float As[16][64];
  __shared__ float Bs[16][64];
  const int tid = threadIdx.x;
  const int n0 = blockIdx.x * 64;   // vocab col
  const int m0 = blockIdx.y * 64;   // row (b*128+t)
  float acc[4][4] = {};
  const int rl = tid >> 2;
  const int kq = (tid & 3) * 4;
  const int tm = tid & 15, tn = tid >> 4;
  for (int k0 = 0; k0 < NH; k0 += 16) {
    __syncthreads();
    float4 av = *(const float4*)(A + (long long)(m0 + rl) * NH + k0 + kq);
    float4 bv = *(const float4*)(Bw + (long long)(n0 + rl) * NH + k0 + kq);
    As[kq + 0][rl] = av.x; As[kq + 1][rl] = av.y; As[kq + 2][rl] = av.z; As[kq + 3][rl] = av.w;
    Bs[kq + 0][rl] = bv.x; Bs[kq + 1][rl] = bv.y; Bs[kq + 2][rl] = bv.z; Bs[kq + 3][rl] = bv.w;
    __syncthreads();
#pragma unroll
    for (int kk = 0; kk < 16; ++kk) {
      float4 a = *(const float4*)&As[kk][tm * 4];
      float4 b = *(const float4*)&Bs[kk][tn * 4];
      float ar[4] = {a.x, a.y, a.z, a.w}, br[4] = {b.x, b.y, b.z, b.w};
#pragma unroll
      for (int i = 0; i < 4; ++i)
#pragma unroll
        for (int j = 0; j < 4; ++j) acc[i][j] = fmaf(ar[i], br[j], acc[i][j]);
    }
  }
#pragma unroll
  for (int i = 0; i < 4; ++i) {
    int r = m0 + tm * 4 + i;
#pragma unroll
    for (int j = 0; j < 4; ++j) {
      int c = n0 + tn * 4 + j;
      C[(long long)r * NV + c] = acc[i][j] + bias[c];
    }
  }
}

// ---------------- launch ----------------
extern "C" void kernel_launch(void* const* d_in, const int* in_sizes, int n_in,
                              void* d_out, int out_size, void* d_ws, size_t ws_size,
                              hipStream_t stream) {
  const int* tv = (const int*)d_in[0];
  const float* dh = (const float*)d_in[1];
  const float* enc = (const float*)d_in[2];
  const int* mask = (const int*)d_in[3];
  const float* emb = (const float*)d_in[4];
  const float* w_ih = (const float*)d_in[5];
  const float* w_hh = (const float*)d_in[6];
  const float* b_ih = (const float*)d_in[7];
  const float* b_hh = (const float*)d_in[8];
  const float* lin_w = (const float*)d_in[9];
  const float* out_w = (const float*)d_in[10];
  const float* out_b = (const float*)d_in[11];
  float* dout = (float*)d_out;   // reference outputs are float32 -> d_out is float*
  char* ws = (char*)d_ws;
  if (ws_size < WS_NEED) return;

  unsigned int* cnt = (unsigned int*)(ws + CNT_OFF);
  float* whhT = (float*)(ws + WHHT_OFF);
  float* gi_all = (float*)(ws + GI_OFF);
  float* h_all = (float*)(ws + HALL_OFF);
  float* comb = (float*)(ws + COMB_OFF);
  float* attf = (float*)(ws + ATT_OFF);

  float* d_scores = dout;                                  // [B,T,V]
  float* d_hf = dout + (long long)NB * NT * NV;            // [1,B,H]
  float* d_attn = d_hf + NB * NH;                          // [T,B,S]

  k_prep<<<1024, 256, 0, stream>>>(w_hh, dh, whhT, h_all, cnt);
  k_gi<<<dim3(24, 32), 256, 0, stream>>>(tv, emb, w_ih, b_ih, gi_all);
  k_rec<<<64, 256, 0, stream>>>(whhT, gi_all, b_hh, h_all, cnt, d_hf);
  k_attn<<<2048, 256, 0, stream>>>(h_all, enc, mask, d_attn, comb);
  k_att_lin<<<dim3(8, 32), 256, 0, stream>>>(comb, lin_w, attf);
  k_out32<<<dim3(500, 32), 256, 0, stream>>>(attf, out_w, out_b, d_scores);
}

// Round 8
// 2042.336 us; speedup vs baseline: 1.5563x; 1.5563x over previous
//
#include <hip/hip_runtime.h>
#include <hip/hip_bf16.h>

#define NV 32000
#define NE 512
#define NH 512
#define NB 16
#define NT 128
#define NS 128

typedef __bf16 bf16x8 __attribute__((ext_vector_type(8)));
typedef float f32x4 __attribute__((ext_vector_type(4)));
typedef const __attribute__((address_space(1))) unsigned int gu32;
typedef __attribute__((address_space(3))) unsigned int lu32;

// ---------------- workspace layout (bytes) ----------------
static constexpr size_t CNT_OFF  = 0;                                     // 1024 uints
static constexpr size_t WHH2_OFF = 4096;                                  // float2[256][1536]
static constexpr size_t GI_OFF   = WHH2_OFF + (size_t)256*1536*8;         // [T][B][1536] f32
static constexpr size_t HALL_OFF = GI_OFF + (size_t)NT*NB*3*NH*4;         // [T+1][B][512] f32
static constexpr size_t MIX_OFF  = HALL_OFF + (size_t)(NT+1)*NB*NH*4;     // [B*T][512] f32
static constexpr size_t ATTB_OFF = MIX_OFF + (size_t)NB*NT*NH*4;          // [B*T][512] bf16
static constexpr size_t OWB_OFF  = ATTB_OFF + (size_t)NB*NT*NH*2;         // [V][512] bf16
static constexpr size_t WS_NEED  = OWB_OFF + (size_t)NV*NH*2;             // ~59.0 MB (<60.3 confirmed)

// ---------------- K1: prep (whh float2 repack, out_w->bf16, h0, counters) ----------------
__global__ __launch_bounds__(256) void k_prep(const float* __restrict__ w_hh,
                                              const float* __restrict__ dh,
                                              const float* __restrict__ out_w,
                                              float2* __restrict__ whh2,
                                              float* __restrict__ h_all,
                                              __bf16* __restrict__ owb,
                                              unsigned int* __restrict__ cnt) {
  long long i0 = (long long)blockIdx.x * blockDim.x + threadIdx.x;
  long long stride = (long long)gridDim.x * blockDim.x;
  // out_w -> bf16
  long long n4 = (long long)NV * NH / 4;
  for (long long i = i0; i < n4; i += stride) {
    float4 v = ((const float4*)out_w)[i];
    union { __bf16 b[4]; float2 f2; } u;
    u.b[0] = (__bf16)v.x; u.b[1] = (__bf16)v.y; u.b[2] = (__bf16)v.z; u.b[3] = (__bf16)v.w;
    *((float2*)(owb + 4 * i)) = u.f2;
  }
  // w_hh [1536][512] -> whh2[k2][j] = (W[j][2k2], W[j][2k2+1])
  for (long long i = i0; i < (long long)256 * 1536; i += stride) {
    int k2 = (int)(i / 1536), j = (int)(i % 1536);
    whh2[i] = make_float2(w_hh[(long long)j * NH + 2 * k2],
                          w_hh[(long long)j * NH + 2 * k2 + 1]);
  }
  // h_all[0] = decoder_hidden
  for (long long i = i0; i < NB * NH; i += stride) h_all[i] = dh[i];
  // barrier counters
  for (long long i = i0; i < 1024; i += stride) cnt[i] = 0u;
}

// ---------------- K2: gi = emb(text_vec) @ w_ih^T + b_ih  (fp32, 64x64 tile) ----------------
__global__ __launch_bounds__(256) void k_gi(const int* __restrict__ tv,
                                            const float* __restrict__ emb,
                                            const float* __restrict__ w_ih,
                                            const float* __restrict__ b_ih,
                                            float* __restrict__ gi_all) {
  __shared__ float As[16][64];
  __shared__ float Bs[16][64];
  const int tid = threadIdx.x;
  const int n0 = blockIdx.x * 64;   // j (0..1535)
  const int m0 = blockIdx.y * 64;   // bt row (0..2047)
  float acc[4][4] = {};
  const int rl = tid >> 2;          // 0..63
  const int kq = (tid & 3) * 4;     // 0,4,8,12
  const int tvr = tv[m0 + rl];
  const float* arow = emb + (long long)tvr * NE;
  const int tm = tid & 15, tn = tid >> 4;
  for (int k0 = 0; k0 < NE; k0 += 16) {
    __syncthreads();
    float4 av = make_float4(0.f, 0.f, 0.f, 0.f);
    if (tvr != 0) av = *(const float4*)(arow + k0 + kq);
    float4 bv = *(const float4*)(w_ih + (long long)(n0 + rl) * NE + k0 + kq);
    As[kq + 0][rl] = av.x; As[kq + 1][rl] = av.y; As[kq + 2][rl] = av.z; As[kq + 3][rl] = av.w;
    Bs[kq + 0][rl] = bv.x; Bs[kq + 1][rl] = bv.y; Bs[kq + 2][rl] = bv.z; Bs[kq + 3][rl] = bv.w;
    __syncthreads();
#pragma unroll
    for (int kk = 0; kk < 16; ++kk) {
      float4 a = *(const float4*)&As[kk][tm * 4];
      float4 b = *(const float4*)&Bs[kk][tn * 4];
      float ar[4] = {a.x, a.y, a.z, a.w}, br[4] = {b.x, b.y, b.z, b.w};
#pragma unroll
      for (int i = 0; i < 4; ++i)
#pragma unroll
        for (int j = 0; j < 4; ++j) acc[i][j] = fmaf(ar[i], br[j], acc[i][j]);
    }
  }
#pragma unroll
  for (int i = 0; i < 4; ++i) {
    int r = m0 + tm * 4 + i;                 // r = b*128 + t
    long long gb = (long long)((r & 127) * 16 + (r >> 7)) * (3 * NH);  // (t*16+b)*1536
#pragma unroll
    for (int j = 0; j < 4; ++j) {
      int jg = n0 + tn * 4 + j;
      gi_all[gb + jg] = acc[i][j] + b_ih[jg];
    }
  }
}

// ---------------- K3: GRU recurrence. 64 blocks (16 b x 4 sub) x 1024 threads ----------------
__global__ __launch_bounds__(1024) void k_rec(const float2* __restrict__ whh2,
                                              const float* __restrict__ gi_all,
                                              const float* __restrict__ b_hh,
                                              float* __restrict__ h_all,
                                              unsigned int* __restrict__ cnt,
                                              float* __restrict__ d_hf) {
  const int tid = threadIdx.x;
  const int b = blockIdx.x & 15, sub = blockIdx.x >> 4;   // 4 subs of b land on same XCD (bid%8 equal)
  const int hl = tid & 127, kc = tid >> 7;                // 128 h x 8 k-chunks
  const int h = sub * 128 + hl;
  __shared__ float hbuf[512];
  __shared__ float part[3][8][128];
  const float bhr = b_hh[h], bhz = b_hh[512 + h], bhn = b_hh[1024 + h];
  unsigned int* flag = &cnt[b * 64];
  for (int t = 0; t < NT; ++t) {
    float* hsrc = h_all + (long long)(t * 16 + b) * 512;
    if (tid < 512)
      hbuf[tid] = __hip_atomic_load(hsrc + tid, __ATOMIC_RELAXED, __HIP_MEMORY_SCOPE_AGENT);
    __syncthreads();
    float ar = 0.f, az = 0.f, an = 0.f;
    const int k2base = kc * 32;
#pragma unroll 8
    for (int q = 0; q < 32; ++q) {
      int k2 = k2base + q;
      float hx = hbuf[2 * k2], hy = hbuf[2 * k2 + 1];
      const float2* wr = whh2 + (long long)k2 * 1536;
      float2 w0 = wr[h], w1 = wr[512 + h], w2 = wr[1024 + h];
      ar = fmaf(hx, w0.x, ar); ar = fmaf(hy, w0.y, ar);
      az = fmaf(hx, w1.x, az); az = fmaf(hy, w1.y, az);
      an = fmaf(hx, w2.x, an); an = fmaf(hy, w2.y, an);
    }
    part[0][kc][hl] = ar; part[1][kc][hl] = az; part[2][kc][hl] = an;
    __syncthreads();
    if (kc == 0) {
      float sr = 0.f, sz = 0.f, sn = 0.f;
#pragma unroll
      for (int c = 0; c < 8; ++c) {
        sr += part[0][c][hl]; sz += part[1][c][hl]; sn += part[2][c][hl];
      }
      sr += bhr; sz += bhz; sn += bhn;
      const float* gi = gi_all + (long long)(t * 16 + b) * 1536;
      float r = 1.f / (1.f + expf(-(gi[h] + sr)));
      float z = 1.f / (1.f + expf(-(gi[512 + h] + sz)));
      float n = tanhf(gi[1024 + h] + r * sn);
      float hp = hbuf[h];
      float hv = (1.f - z) * n + z * hp;
      __hip_atomic_store(&h_all[(long long)((t + 1) * 16 + b) * 512 + h], hv,
                         __ATOMIC_RELAXED, __HIP_MEMORY_SCOPE_AGENT);
      if (t == NT - 1) d_hf[b * 512 + h] = hv;
    }
    __syncthreads();
    if (t < NT - 1) {
      if (tid == 0) {
        __hip_atomic_fetch_add(flag, 1u, __ATOMIC_RELEASE, __HIP_MEMORY_SCOPE_AGENT);
        unsigned int target = 4u * (unsigned)(t + 1);
        int g = 0;
        while (__hip_atomic_load(flag, __ATOMIC_ACQUIRE, __HIP_MEMORY_SCOPE_AGENT) < target &&
               ++g < (1 << 22)) {}
      }
      __syncthreads();
    }
  }
}

// ---------------- K4: attention per (t,b): scores->softmax->mix ----------------
__global__ __launch_bounds__(256) void k_attn(const float* __restrict__ h_all,
                                              const float* __restrict__ enc,
                                              const int* __restrict__ mask,
                                              float* __restrict__ d_attn,
                                              float* __restrict__ mix) {
  const int g = blockIdx.x;
  const int t = g >> 4, b = g & 15;
  const int tid = threadIdx.x;
  __shared__ float hb[512];
  __shared__ float red[256];
  __shared__ float wb[128];
  __shared__ float smax, ssum;
  const float* hsrc = h_all + (long long)((t + 1) * 16 + b) * 512;
  hb[tid] = hsrc[tid];
  hb[tid + 256] = hsrc[tid + 256];
  __syncthreads();
  const int s = tid & 127, half = tid >> 7;
  const float* erow = enc + (long long)(b * 128 + s) * 512 + half * 256;
  float p = 0.f;
#pragma unroll 8
  for (int k = 0; k < 256; ++k) p = fmaf(hb[half * 256 + k], erow[k], p);
  red[tid] = p;
  __syncthreads();
  float sc = 0.f;
  if (tid < 128) {
    sc = red[tid] + red[tid + 128];
    if (mask[b * 128 + tid] == 0) sc = -1e6f;
    wb[tid] = sc;
  }
  __syncthreads();
  if (tid < 64) {
    float m2 = fmaxf(wb[tid], wb[tid + 64]);
    for (int off = 32; off; off >>= 1) m2 = fmaxf(m2, __shfl_down(m2, off));
    if (tid == 0) smax = m2;
  }
  __syncthreads();
  if (tid < 128) wb[tid] = expf(sc - smax);
  __syncthreads();
  if (tid < 64) {
    float s2 = wb[tid] + wb[tid + 64];
    for (int off = 32; off; off >>= 1) s2 += __shfl_down(s2, off);
    if (tid == 0) ssum = s2;
  }
  __syncthreads();
  float inv = 1.f / ssum;
  if (tid < 128) {
    float w = wb[tid] * inv;
    wb[tid] = w;
    d_attn[(long long)(t * 16 + b) * 128 + tid] = w;
  }
  __syncthreads();
  long long mrow = (long long)(b * 128 + t) * 512;
  for (int hh = tid; hh < 512; hh += 256) {
    float acc = 0.f;
#pragma unroll 8
    for (int s2 = 0; s2 < 128; ++s2) acc = fmaf(wb[s2], enc[(long long)(b * 128 + s2) * 512 + hh], acc);
    mix[mrow + hh] = acc;
  }
}

// ---------------- K5: attended = tanh([h,mix] @ lin_out_w^T) -> bf16 ----------------
__global__ __launch_bounds__(256) void k_att_lin(const float* __restrict__ h_all,
                                                 const float* __restrict__ mix,
                                                 const float* __restrict__ W,
                                                 __bf16* __restrict__ attout) {
  __shared__ float As[16][64];
  __shared__ float Bs[16][64];
  const int tid = threadIdx.x;
  const int n0 = blockIdx.x * 64;   // o (0..511)
  const int m0 = blockIdx.y * 64;   // r (0..2047)
  float acc[4][4] = {};
  const int rl = tid >> 2;
  const int kq = (tid & 3) * 4;
  const int tm = tid & 15, tn = tid >> 4;
  const int r_a = m0 + rl;
  const int b_a = r_a >> 7, t_a = r_a & 127;
  const float* hrow = h_all + (long long)((t_a + 1) * 16 + b_a) * 512;
  const float* mrow = mix + (long long)r_a * 512;
  for (int k0 = 0; k0 < 1024; k0 += 16) {
    __syncthreads();
    float4 av = (k0 < 512) ? *(const float4*)(hrow + k0 + kq)
                           : *(const float4*)(mrow + (k0 - 512) + kq);
    float4 bv = *(const float4*)(W + (long long)(n0 + rl) * 1024 + k0 + kq);
    As[kq + 0][rl] = av.x; As[kq + 1][rl] = av.y; As[kq + 2][rl] = av.z; As[kq + 3][rl] = av.w;
    Bs[kq + 0][rl] = bv.x; Bs[kq + 1][rl] = bv.y; Bs[kq + 2][rl] = bv.z; Bs[kq + 3][rl] = bv.w;
    __syncthreads();
#pragma unroll
    for (int kk = 0; kk < 16; ++kk) {
      float4 a = *(const float4*)&As[kk][tm * 4];
      float4 b = *(const float4*)&Bs[kk][tn * 4];
      float ar[4] = {a.x, a.y, a.z, a.w}, br[4] = {b.x, b.y, b.z, b.w};
#pragma unroll
      for (int i = 0; i < 4; ++i)
#pragma unroll
        for (int j = 0; j < 4; ++j) acc[i][j] = fmaf(ar[i], br[j], acc[i][j]);
    }
  }
#pragma unroll
  for (int i = 0; i < 4; ++i) {
    int r = m0 + tm * 4 + i;
#pragma unroll
    for (int j = 0; j < 4; ++j) {
      int o = n0 + tn * 4 + j;
      attout[(long long)r * 512 + o] = (__bf16)tanhf(acc[i][j]);
    }
  }
}

// ---------------- K6: scores = attended @ out_w^T + out_b  (bf16 MFMA, f32 out) ----------------
__global__ __launch_bounds__(256) void k_out(const __bf16* __restrict__ Abf,
                                             const __bf16* __restrict__ Bbf,
                                             const float* __restrict__ bias,
                                             float* __restrict__ Cout) {
  __shared__ __bf16 Al[128 * 32];
  __shared__ __bf16 Bl[128 * 32];
  const int tid = threadIdx.x;
  const int lane = tid & 63;
  const int wave = tid >> 6;
  const int wm = wave >> 1, wn = wave & 1;
  const int m0 = blockIdx.y * 128, n0 = blockIdx.x * 128;
  f32x4 acc[4][4] = {};
  const int lrow = lane >> 2;        // staging row-in-chunk
  const int lcol = (lane & 3) * 8;   // staging col (elements)
  const int lm = lane & 15, lc = lane >> 4;
  for (int ks = 0; ks < 16; ++ks) {
    const int k0 = ks * 32;
    __syncthreads();
#pragma unroll
    for (int i = 0; i < 2; ++i) {
      int chunk = wave * 2 + i;
      int r = chunk * 16 + lrow;
      const __bf16* ga = Abf + (long long)(m0 + r) * NH + k0 + lcol;
      const __bf16* gb = Bbf + (long long)(n0 + r) * NH + k0 + lcol;
      __builtin_amdgcn_global_load_lds((gu32*)ga, (lu32*)((char*)Al + chunk * 1024), 16, 0, 0);
      __builtin_amdgcn_global_load_lds((gu32*)gb, (lu32*)((char*)Bl + chunk * 1024), 16, 0, 0);
    }
    __syncthreads();
    bf16x8 af[4], bfr[4];
#pragma unroll
    for (int i = 0; i < 4; ++i) af[i] = *(const bf16x8*)&Al[(wm * 64 + i * 16 + lm) * 32 + lc * 8];
#pragma unroll
    for (int j = 0; j < 4; ++j) bfr[j] = *(const bf16x8*)&Bl[(wn * 64 + j * 16 + lm) * 32 + lc * 8];
#pragma unroll
    for (int i = 0; i < 4; ++i)
#pragma unroll
      for (int j = 0; j < 4; ++j)
        acc[i][j] = __builtin_amdgcn_mfma_f32_16x16x32_bf16(af[i], bfr[j], acc[i][j], 0, 0, 0);
  }
#pragma unroll
  for (int j = 0; j < 4; ++j) {
    int c = n0 + wn * 64 + j * 16 + lm;
    float bv = bias[c];
#pragma unroll
    for (int i = 0; i < 4; ++i) {
      int rb = m0 + wm * 64 + i * 16 + lc * 4;
#pragma unroll
      for (int q = 0; q < 4; ++q)
        Cout[(long long)(rb + q) * NV + c] = acc[i][j][q] + bv;
    }
  }
}

// ---------------- launch ----------------
extern "C" void kernel_launch(void* const* d_in, const int* in_sizes, int n_in,
                              void* d_out, int out_size, void* d_ws, size_t ws_size,
                              hipStream_t stream) {
  const int* tv = (const int*)d_in[0];
  const float* dh = (const float*)d_in[1];
  const float* enc = (const float*)d_in[2];
  const int* mask = (const int*)d_in[3];
  const float* emb = (const float*)d_in[4];
  const float* w_ih = (const float*)d_in[5];
  const float* w_hh = (const float*)d_in[6];
  const float* b_ih = (const float*)d_in[7];
  const float* b_hh = (const float*)d_in[8];
  const float* lin_w = (const float*)d_in[9];
  const float* out_w = (const float*)d_in[10];
  const float* out_b = (const float*)d_in[11];
  float* dout = (float*)d_out;   // outputs are float32
  char* ws = (char*)d_ws;
  if (ws_size < WS_NEED) return;

  unsigned int* cnt = (unsigned int*)(ws + CNT_OFF);
  float2* whh2 = (float2*)(ws + WHH2_OFF);
  float* gi_all = (float*)(ws + GI_OFF);
  float* h_all = (float*)(ws + HALL_OFF);
  float* mixb = (float*)(ws + MIX_OFF);
  __bf16* attb = (__bf16*)(ws + ATTB_OFF);
  __bf16* owb = (__bf16*)(ws + OWB_OFF);

  float* d_scores = dout;                                  // [B,T,V]
  float* d_hf = dout + (long long)NB * NT * NV;            // [1,B,H]
  float* d_attn = d_hf + NB * NH;                          // [T,B,S]

  k_prep<<<1024, 256, 0, stream>>>(w_hh, dh, out_w, whh2, h_all, owb, cnt);
  k_gi<<<dim3(24, 32), 256, 0, stream>>>(tv, emb, w_ih, b_ih, gi_all);
  k_rec<<<64, 1024, 0, stream>>>(whh2, gi_all, b_hh, h_all, cnt, d_hf);
  k_attn<<<2048, 256, 0, stream>>>(h_all, enc, mask, d_attn, mixb);
  k_att_lin<<<dim3(8, 32), 256, 0, stream>>>(h_all, mixb, lin_w, attb);
  k_out<<<dim3(250, 16), 256, 0, stream>>>(attb, owb, out_b, d_scores);
}

// Round 9
// 843.471 us; speedup vs baseline: 3.7683x; 2.4213x over previous
//
#include <hip/hip_runtime.h>
#include <hip/hip_bf16.h>

#define NV 32000
#define NE 512
#define NH 512
#define NB 16
#define NT 128
#define NS 128

typedef __bf16 bf16x8 __attribute__((ext_vector_type(8)));
typedef float f32x4 __attribute__((ext_vector_type(4)));
typedef const __attribute__((address_space(1))) unsigned int gu32;
typedef __attribute__((address_space(3))) unsigned int lu32;

// ---------------- workspace layout (bytes) ----------------
static constexpr size_t CNT_OFF  = 0;                                     // 1024 uints
static constexpr size_t WHHT_OFF = 4096;                                  // [512][1536] f32 (W_hh^T)
static constexpr size_t GI_OFF   = WHHT_OFF + (size_t)3*NH*NH*4;          // [T][B][1536] f32
static constexpr size_t HALL_OFF = GI_OFF + (size_t)NT*NB*3*NH*4;         // [T+1][B][512] f32
static constexpr size_t MIX_OFF  = HALL_OFF + (size_t)(NT+1)*NB*NH*4;     // [B*T][512] f32
static constexpr size_t ATTB_OFF = MIX_OFF + (size_t)NB*NT*NH*4;          // [B*T][512] bf16
static constexpr size_t OWB_OFF  = ATTB_OFF + (size_t)NB*NT*NH*2;         // [V][512] bf16
static constexpr size_t WS_NEED  = OWB_OFF + (size_t)NV*NH*2;             // ~59.0 MB

// ---------------- K1: prep (w_hh transpose, out_w->bf16, h0, counters) ----------------
__global__ __launch_bounds__(256) void k_prep(const float* __restrict__ w_hh,
                                              const float* __restrict__ dh,
                                              const float* __restrict__ out_w,
                                              float* __restrict__ whhT,
                                              float* __restrict__ h_all,
                                              __bf16* __restrict__ owb,
                                              unsigned int* __restrict__ cnt) {
  long long i0 = (long long)blockIdx.x * blockDim.x + threadIdx.x;
  long long stride = (long long)gridDim.x * blockDim.x;
  // out_w -> bf16
  long long n4 = (long long)NV * NH / 4;
  for (long long i = i0; i < n4; i += stride) {
    float4 v = ((const float4*)out_w)[i];
    union { __bf16 b[4]; float2 f2; } u;
    u.b[0] = (__bf16)v.x; u.b[1] = (__bf16)v.y; u.b[2] = (__bf16)v.z; u.b[3] = (__bf16)v.w;
    *((float2*)(owb + 4 * i)) = u.f2;
  }
  // w_hh [1536][512] -> whhT [512][1536]
  for (long long i = i0; i < (long long)3 * NH * NH; i += stride) {
    int k = (int)(i / (3 * NH)), j = (int)(i % (3 * NH));
    whhT[i] = w_hh[(long long)j * NH + k];
  }
  // h_all[0] = decoder_hidden
  for (long long i = i0; i < NB * NH; i += stride) h_all[i] = dh[i];
  // barrier counters
  for (long long i = i0; i < 1024; i += stride) cnt[i] = 0u;
}

// ---------------- K2: gi = emb(text_vec) @ w_ih^T + b_ih  (fp32, 64x64 tile) ----------------
__global__ __launch_bounds__(256) void k_gi(const int* __restrict__ tv,
                                            const float* __restrict__ emb,
                                            const float* __restrict__ w_ih,
                                            const float* __restrict__ b_ih,
                                            float* __restrict__ gi_all) {
  __shared__ float As[16][64];
  __shared__ float Bs[16][64];
  const int tid = threadIdx.x;
  const int n0 = blockIdx.x * 64;   // j (0..1535)
  const int m0 = blockIdx.y * 64;   // bt row (0..2047)
  float acc[4][4] = {};
  const int rl = tid >> 2;          // 0..63
  const int kq = (tid & 3) * 4;     // 0,4,8,12
  const int tvr = tv[m0 + rl];
  const float* arow = emb + (long long)tvr * NE;
  const int tm = tid & 15, tn = tid >> 4;
  for (int k0 = 0; k0 < NE; k0 += 16) {
    __syncthreads();
    float4 av = make_float4(0.f, 0.f, 0.f, 0.f);
    if (tvr != 0) av = *(const float4*)(arow + k0 + kq);
    float4 bv = *(const float4*)(w_ih + (long long)(n0 + rl) * NE + k0 + kq);
    As[kq + 0][rl] = av.x; As[kq + 1][rl] = av.y; As[kq + 2][rl] = av.z; As[kq + 3][rl] = av.w;
    Bs[kq + 0][rl] = bv.x; Bs[kq + 1][rl] = bv.y; Bs[kq + 2][rl] = bv.z; Bs[kq + 3][rl] = bv.w;
    __syncthreads();
#pragma unroll
    for (int kk = 0; kk < 16; ++kk) {
      float4 a = *(const float4*)&As[kk][tm * 4];
      float4 b = *(const float4*)&Bs[kk][tn * 4];
      float ar[4] = {a.x, a.y, a.z, a.w}, br[4] = {b.x, b.y, b.z, b.w};
#pragma unroll
      for (int i = 0; i < 4; ++i)
#pragma unroll
        for (int j = 0; j < 4; ++j) acc[i][j] = fmaf(ar[i], br[j], acc[i][j]);
    }
  }
#pragma unroll
  for (int i = 0; i < 4; ++i) {
    int r = m0 + tm * 4 + i;                 // r = b*128 + t
    long long gb = (long long)((r & 127) * 16 + (r >> 7)) * (3 * NH);  // (t*16+b)*1536
#pragma unroll
    for (int j = 0; j < 4; ++j) {
      int jg = n0 + tn * 4 + j;
      gi_all[gb + jg] = acc[i][j] + b_ih[jg];
    }
  }
}

// ---------------- K3: GRU recurrence. 128 blocks (16 b x 8 sub) x 512 threads ----------------
// Weights live in VGPRs (192 f32/thread, loaded once). Exchange via agent atomics +
// release fetch_add / relaxed poll + single acquire.
__global__ __launch_bounds__(512, 2) void k_rec(const float* __restrict__ whhT,
                                                const float* __restrict__ gi_all,
                                                const float* __restrict__ b_hh,
                                                float* __restrict__ h_all,
                                                unsigned int* __restrict__ cnt,
                                                float* __restrict__ d_hf) {
  const int tid = threadIdx.x;
  const int b = blockIdx.x & 15, sub = blockIdx.x >> 4;   // same-b blocks share bid%8 -> same XCD (heuristic)
  const int hl = tid & 63, kc = tid >> 6;                 // 64 h x 8 k-chunks
  const int j = sub * 64 + hl;                            // this thread's output h (for its kc slice)
  __shared__ float hbuf[512];
  __shared__ float part[3][8][64];
  unsigned int* flag = &cnt[b * 64];

  // ---- preload weights into registers: wg[g][q] = W^T[kc*64+q][g*512+j]
  float wg[3][64];
#pragma unroll
  for (int g = 0; g < 3; ++g) {
    const float* wp = whhT + (long long)(kc * 64) * 1536 + g * 512 + j;
#pragma unroll
    for (int q = 0; q < 64; ++q) wg[g][q] = wp[(long long)q * 1536];
  }
  // biases for finalize threads
  float bhr = 0.f, bhz = 0.f, bhn = 0.f;
  if (tid < 64) {
    bhr = b_hh[sub * 64 + tid];
    bhz = b_hh[512 + sub * 64 + tid];
    bhn = b_hh[1024 + sub * 64 + tid];
  }

  for (int t = 0; t < NT; ++t) {
    // prefetch gi for finalize (HBM-latency hidden under the dot)
    float gr = 0.f, gz = 0.f, gn = 0.f;
    if (tid < 64) {
      const float* gi = gi_all + (long long)(t * 16 + b) * 1536;
      gr = gi[sub * 64 + tid];
      gz = gi[512 + sub * 64 + tid];
      gn = gi[1024 + sub * 64 + tid];
    }
    // stage h_t
    float* hsrc = h_all + (long long)(t * 16 + b) * 512;
    hbuf[tid] = __hip_atomic_load(hsrc + tid, __ATOMIC_RELAXED, __HIP_MEMORY_SCOPE_AGENT);
    __syncthreads();
    // dot: 192 FMA from registers
    float ar = 0.f, az = 0.f, an = 0.f;
#pragma unroll
    for (int q4 = 0; q4 < 4; ++q4) {
      float4 h4[4];
#pragma unroll
      for (int u = 0; u < 4; ++u) h4[u] = *(const float4*)&hbuf[kc * 64 + q4 * 16 + u * 4];
#pragma unroll
      for (int u = 0; u < 4; ++u) {
        const float hh[4] = {h4[u].x, h4[u].y, h4[u].z, h4[u].w};
#pragma unroll
        for (int v = 0; v < 4; ++v) {
          const int q = q4 * 16 + u * 4 + v;
          ar = fmaf(hh[v], wg[0][q], ar);
          az = fmaf(hh[v], wg[1][q], az);
          an = fmaf(hh[v], wg[2][q], an);
        }
      }
    }
    part[0][kc][hl] = ar; part[1][kc][hl] = az; part[2][kc][hl] = an;
    __syncthreads();
    if (tid < 64) {
      float sr = bhr, sz = bhz, sn = bhn;
#pragma unroll
      for (int c = 0; c < 8; ++c) {
        sr += part[0][c][tid]; sz += part[1][c][tid]; sn += part[2][c][tid];
      }
      float r = 1.f / (1.f + expf(-(gr + sr)));
      float z = 1.f / (1.f + expf(-(gz + sz)));
      float n = tanhf(gn + r * sn);
      float hp = hbuf[sub * 64 + tid];
      float hv = (1.f - z) * n + z * hp;
      __hip_atomic_store(&h_all[(long long)((t + 1) * 16 + b) * 512 + sub * 64 + tid], hv,
                         __ATOMIC_RELAXED, __HIP_MEMORY_SCOPE_AGENT);
      if (t == NT - 1) d_hf[b * 512 + sub * 64 + tid] = hv;
    }
    __syncthreads();   // drains the h stores (vmcnt) before the release-add
    if (t < NT - 1) {
      if (tid == 0) {
        __hip_atomic_fetch_add(flag, 1u, __ATOMIC_RELEASE, __HIP_MEMORY_SCOPE_AGENT);
        unsigned int target = 8u * (unsigned)(t + 1);
        int g = 0;
        while (__hip_atomic_load(flag, __ATOMIC_RELAXED, __HIP_MEMORY_SCOPE_AGENT) < target &&
               ++g < (1 << 24)) {}
        (void)__hip_atomic_load(flag, __ATOMIC_ACQUIRE, __HIP_MEMORY_SCOPE_AGENT);  // one inv, not per-poll
      }
      __syncthreads();
    }
  }
}

// ---------------- K4: attention per (t,b): scores->softmax->mix ----------------
__global__ __launch_bounds__(256) void k_attn(const float* __restrict__ h_all,
                                              const float* __restrict__ enc,
                                              const int* __restrict__ mask,
                                              float* __restrict__ d_attn,
                                              float* __restrict__ mix) {
  const int g = blockIdx.x;
  const int t = g >> 4, b = g & 15;
  const int tid = threadIdx.x;
  __shared__ float hb[512];
  __shared__ float red[256];
  __shared__ float wb[128];
  __shared__ float smax, ssum;
  const float* hsrc = h_all + (long long)((t + 1) * 16 + b) * 512;
  hb[tid] = hsrc[tid];
  hb[tid + 256] = hsrc[tid + 256];
  __syncthreads();
  const int s = tid & 127, half = tid >> 7;
  const float* erow = enc + (long long)(b * 128 + s) * 512 + half * 256;
  float p = 0.f;
#pragma unroll 8
  for (int k = 0; k < 256; ++k) p = fmaf(hb[half * 256 + k], erow[k], p);
  red[tid] = p;
  __syncthreads();
  float sc = 0.f;
  if (tid < 128) {
    sc = red[tid] + red[tid + 128];
    if (mask[b * 128 + tid] == 0) sc = -1e6f;
    wb[tid] = sc;
  }
  __syncthreads();
  if (tid < 64) {
    float m2 = fmaxf(wb[tid], wb[tid + 64]);
    for (int off = 32; off; off >>= 1) m2 = fmaxf(m2, __shfl_down(m2, off));
    if (tid == 0) smax = m2;
  }
  __syncthreads();
  if (tid < 128) wb[tid] = expf(sc - smax);
  __syncthreads();
  if (tid < 64) {
    float s2 = wb[tid] + wb[tid + 64];
    for (int off = 32; off; off >>= 1) s2 += __shfl_down(s2, off);
    if (tid == 0) ssum = s2;
  }
  __syncthreads();
  float inv = 1.f / ssum;
  if (tid < 128) {
    float w = wb[tid] * inv;
    wb[tid] = w;
    d_attn[(long long)(t * 16 + b) * 128 + tid] = w;
  }
  __syncthreads();
  long long mrow = (long long)(b * 128 + t) * 512;
  for (int hh = tid; hh < 512; hh += 256) {
    float acc = 0.f;
#pragma unroll 8
    for (int s2 = 0; s2 < 128; ++s2) acc = fmaf(wb[s2], enc[(long long)(b * 128 + s2) * 512 + hh], acc);
    mix[mrow + hh] = acc;
  }
}

// ---------------- K5: attended = tanh([h,mix] @ lin_out_w^T) -> bf16 ----------------
__global__ __launch_bounds__(256) void k_att_lin(const float* __restrict__ h_all,
                                                 const float* __restrict__ mix,
                                                 const float* __restrict__ W,
                                                 __bf16* __restrict__ attout) {
  __shared__ float As[16][64];
  __shared__ float Bs[16][64];
  const int tid = threadIdx.x;
  const int n0 = blockIdx.x * 64;   // o (0..511)
  const int m0 = blockIdx.y * 64;   // r (0..2047)
  float acc[4][4] = {};
  const int rl = tid >> 2;
  const int kq = (tid & 3) * 4;
  const int tm = tid & 15, tn = tid >> 4;
  const int r_a = m0 + rl;
  const int b_a = r_a >> 7, t_a = r_a & 127;
  const float* hrow = h_all + (long long)((t_a + 1) * 16 + b_a) * 512;
  const float* mrow = mix + (long long)r_a * 512;
  for (int k0 = 0; k0 < 1024; k0 += 16) {
    __syncthreads();
    float4 av = (k0 < 512) ? *(const float4*)(hrow + k0 + kq)
                           : *(const float4*)(mrow + (k0 - 512) + kq);
    float4 bv = *(const float4*)(W + (long long)(n0 + rl) * 1024 + k0 + kq);
    As[kq + 0][rl] = av.x; As[kq + 1][rl] = av.y; As[kq + 2][rl] = av.z; As[kq + 3][rl] = av.w;
    Bs[kq + 0][rl] = bv.x; Bs[kq + 1][rl] = bv.y; Bs[kq + 2][rl] = bv.z; Bs[kq + 3][rl] = bv.w;
    __syncthreads();
#pragma unroll
    for (int kk = 0; kk < 16; ++kk) {
      float4 a = *(const float4*)&As[kk][tm * 4];
      float4 b = *(const float4*)&Bs[kk][tn * 4];
      float ar[4] = {a.x, a.y, a.z, a.w}, br[4] = {b.x, b.y, b.z, b.w};
#pragma unroll
      for (int i = 0; i < 4; ++i)
#pragma unroll
        for (int j = 0; j < 4; ++j) acc[i][j] = fmaf(ar[i], br[j], acc[i][j]);
    }
  }
#pragma unroll
  for (int i = 0; i < 4; ++i) {
    int r = m0 + tm * 4 + i;
#pragma unroll
    for (int j = 0; j < 4; ++j) {
      int o = n0 + tn * 4 + j;
      attout[(long long)r * 512 + o] = (__bf16)tanhf(acc[i][j]);
    }
  }
}

// ---------------- K6: scores = attended @ out_w^T + out_b  (bf16 MFMA, f32 out) ----------------
__global__ __launch_bounds__(256) void k_out(const __bf16* __restrict__ Abf,
                                             const __bf16* __restrict__ Bbf,
                                             const float* __restrict__ bias,
                                             float* __restrict__ Cout) {
  __shared__ __bf16 Al[128 * 32];
  __shared__ __bf16 Bl[128 * 32];
  const int tid = threadIdx.x;
  const int lane = tid & 63;
  const int wave = tid >> 6;
  const int wm = wave >> 1, wn = wave & 1;
  const int m0 = blockIdx.y * 128, n0 = blockIdx.x * 128;
  f32x4 acc[4][4] = {};
  const int lrow = lane >> 2;        // staging row-in-chunk
  const int lcol = (lane & 3) * 8;   // staging col (elements)
  const int lm = lane & 15, lc = lane >> 4;
  for (int ks = 0; ks < 16; ++ks) {
    const int k0 = ks * 32;
    __syncthreads();
#pragma unroll
    for (int i = 0; i < 2; ++i) {
      int chunk = wave * 2 + i;
      int r = chunk * 16 + lrow;
      const __bf16* ga = Abf + (long long)(m0 + r) * NH + k0 + lcol;
      const __bf16* gb = Bbf + (long long)(n0 + r) * NH + k0 + lcol;
      __builtin_amdgcn_global_load_lds((gu32*)ga, (lu32*)((char*)Al + chunk * 1024), 16, 0, 0);
      __builtin_amdgcn_global_load_lds((gu32*)gb, (lu32*)((char*)Bl + chunk * 1024), 16, 0, 0);
    }
    __syncthreads();
    bf16x8 af[4], bfr[4];
#pragma unroll
    for (int i = 0; i < 4; ++i) af[i] = *(const bf16x8*)&Al[(wm * 64 + i * 16 + lm) * 32 + lc * 8];
#pragma unroll
    for (int j = 0; j < 4; ++j) bfr[j] = *(const bf16x8*)&Bl[(wn * 64 + j * 16 + lm) * 32 + lc * 8];
#pragma unroll
    for (int i = 0; i < 4; ++i)
#pragma unroll
      for (int j = 0; j < 4; ++j)
        acc[i][j] = __builtin_amdgcn_mfma_f32_16x16x32_bf16(af[i], bfr[j], acc[i][j], 0, 0, 0);
  }
#pragma unroll
  for (int j = 0; j < 4; ++j) {
    int c = n0 + wn * 64 + j * 16 + lm;
    float bv = bias[c];
#pragma unroll
    for (int i = 0; i < 4; ++i) {
      int rb = m0 + wm * 64 + i * 16 + lc * 4;
#pragma unroll
      for (int q = 0; q < 4; ++q)
        Cout[(long long)(rb + q) * NV + c] = acc[i][j][q] + bv;
    }
  }
}

// ---------------- launch ----------------
extern "C" void kernel_launch(void* const* d_in, const int* in_sizes, int n_in,
                              void* d_out, int out_size, void* d_ws, size_t ws_size,
                              hipStream_t stream) {
  const int* tv = (const int*)d_in[0];
  const float* dh = (const float*)d_in[1];
  const float* enc = (const float*)d_in[2];
  const int* mask = (const int*)d_in[3];
  const float* emb = (const float*)d_in[4];
  const float* w_ih = (const float*)d_in[5];
  const float* w_hh = (const float*)d_in[6];
  const float* b_ih = (const float*)d_in[7];
  const float* b_hh = (const float*)d_in[8];
  const float* lin_w = (const float*)d_in[9];
  const float* out_w = (const float*)d_in[10];
  const float* out_b = (const float*)d_in[11];
  float* dout = (float*)d_out;   // outputs are float32
  char* ws = (char*)d_ws;
  if (ws_size < WS_NEED) return;

  unsigned int* cnt = (unsigned int*)(ws + CNT_OFF);
  float* whhT = (float*)(ws + WHHT_OFF);
  float* gi_all = (float*)(ws + GI_OFF);
  float* h_all = (float*)(ws + HALL_OFF);
  float* mixb = (float*)(ws + MIX_OFF);
  __bf16* attb = (__bf16*)(ws + ATTB_OFF);
  __bf16* owb = (__bf16*)(ws + OWB_OFF);

  float* d_scores = dout;                                  // [B,T,V]
  float* d_hf = dout + (long long)NB * NT * NV;            // [1,B,H]
  float* d_attn = d_hf + NB * NH;                          // [T,B,S]

  k_prep<<<1024, 256, 0, stream>>>(w_hh, dh, out_w, whhT, h_all, owb, cnt);
  k_gi<<<dim3(24, 32), 256, 0, stream>>>(tv, emb, w_ih, b_ih, gi_all);
  k_rec<<<128, 512, 0, stream>>>(whhT, gi_all, b_hh, h_all, cnt, d_hf);
  k_attn<<<2048, 256, 0, stream>>>(h_all, enc, mask, d_attn, mixb);
  k_att_lin<<<dim3(8, 32), 256, 0, stream>>>(h_all, mixb, lin_w, attb);
  k_out<<<dim3(250, 16), 256, 0, stream>>>(attb, owb, out_b, d_scores);
}

// Round 10
// 586.949 us; speedup vs baseline: 5.4152x; 1.4370x over previous
//
#include <hip/hip_runtime.h>
#include <hip/hip_bf16.h>

#define NV 32000
#define NE 512
#define NH 512
#define NB 16
#define NT 128
#define NS 128

typedef __bf16 bf16x8 __attribute__((ext_vector_type(8)));
typedef float f32x4 __attribute__((ext_vector_type(4)));
typedef const __attribute__((address_space(1))) unsigned int gu32;
typedef __attribute__((address_space(3))) unsigned int lu32;

// ---------------- workspace layout (bytes) ----------------
static constexpr size_t HTAG_OFF = 0;                                     // [2][16][512] u64 = 128 KB
static constexpr size_t WHHT_OFF = HTAG_OFF + (size_t)2*NB*NH*8;          // [512][1536] f32
static constexpr size_t GI_OFF   = WHHT_OFF + (size_t)3*NH*NH*4;          // [T][B][1536] f32
static constexpr size_t HALL_OFF = GI_OFF + (size_t)NT*NB*3*NH*4;         // [T+1][B][512] f32
static constexpr size_t MIX_OFF  = HALL_OFF + (size_t)(NT+1)*NB*NH*4;     // [B*T][512] f32
static constexpr size_t ATTB_OFF = MIX_OFF + (size_t)NB*NT*NH*4;          // [B*T][512] bf16
static constexpr size_t OWB_OFF  = ATTB_OFF + (size_t)NB*NT*NH*2;         // [V][512] bf16
static constexpr size_t WS_NEED  = OWB_OFF + (size_t)NV*NH*2;             // ~59.1 MB (ws >= 60.3 confirmed by R1-5)

// ---------------- K1: prep (w_hh transpose, out_w->bf16, h0 seed, htag init) ----------------
__global__ __launch_bounds__(256) void k_prep(const float* __restrict__ w_hh,
                                              const float* __restrict__ dh,
                                              const float* __restrict__ out_w,
                                              float* __restrict__ whhT,
                                              float* __restrict__ h_all,
                                              __bf16* __restrict__ owb,
                                              unsigned long long* __restrict__ htag) {
  long long i0 = (long long)blockIdx.x * blockDim.x + threadIdx.x;
  long long stride = (long long)gridDim.x * blockDim.x;
  // out_w -> bf16
  long long n4 = (long long)NV * NH / 4;
  for (long long i = i0; i < n4; i += stride) {
    float4 v = ((const float4*)out_w)[i];
    union { __bf16 b[4]; float2 f2; } u;
    u.b[0] = (__bf16)v.x; u.b[1] = (__bf16)v.y; u.b[2] = (__bf16)v.z; u.b[3] = (__bf16)v.w;
    *((float2*)(owb + 4 * i)) = u.f2;
  }
  // w_hh [1536][512] -> whhT [512][1536]
  for (long long i = i0; i < (long long)3 * NH * NH; i += stride) {
    int k = (int)(i / (3 * NH)), j = (int)(i % (3 * NH));
    whhT[i] = w_hh[(long long)j * NH + k];
  }
  // h_all[0] = h0 ; htag buf0 = {tag=1, h0} ; htag buf1 = 0 (kills cross-replay staleness)
  for (long long i = i0; i < NB * NH; i += stride) {
    float hv = dh[i];
    h_all[i] = hv;
    union { float f; unsigned u; } c; c.f = hv;
    htag[i] = (1ull << 32) | c.u;
    htag[NB * NH + i] = 0ull;
  }
}

// ---------------- K2: gi = emb(text_vec) @ w_ih^T + b_ih  (fp32, 64x64 tile) ----------------
__global__ __launch_bounds__(256) void k_gi(const int* __restrict__ tv,
                                            const float* __restrict__ emb,
                                            const float* __restrict__ w_ih,
                                            const float* __restrict__ b_ih,
                                            float* __restrict__ gi_all) {
  __shared__ float As[16][64];
  __shared__ float Bs[16][64];
  const int tid = threadIdx.x;
  const int n0 = blockIdx.x * 64;   // j (0..1535)
  const int m0 = blockIdx.y * 64;   // bt row (0..2047)
  float acc[4][4] = {};
  const int rl = tid >> 2;          // 0..63
  const int kq = (tid & 3) * 4;     // 0,4,8,12
  const int tvr = tv[m0 + rl];
  const float* arow = emb + (long long)tvr * NE;
  const int tm = tid & 15, tn = tid >> 4;
  for (int k0 = 0; k0 < NE; k0 += 16) {
    __syncthreads();
    float4 av = make_float4(0.f, 0.f, 0.f, 0.f);
    if (tvr != 0) av = *(const float4*)(arow + k0 + kq);
    float4 bv = *(const float4*)(w_ih + (long long)(n0 + rl) * NE + k0 + kq);
    As[kq + 0][rl] = av.x; As[kq + 1][rl] = av.y; As[kq + 2][rl] = av.z; As[kq + 3][rl] = av.w;
    Bs[kq + 0][rl] = bv.x; Bs[kq + 1][rl] = bv.y; Bs[kq + 2][rl] = bv.z; Bs[kq + 3][rl] = bv.w;
    __syncthreads();
#pragma unroll
    for (int kk = 0; kk < 16; ++kk) {
      float4 a = *(const float4*)&As[kk][tm * 4];
      float4 b = *(const float4*)&Bs[kk][tn * 4];
      float ar[4] = {a.x, a.y, a.z, a.w}, br[4] = {b.x, b.y, b.z, b.w};
#pragma unroll
      for (int i = 0; i < 4; ++i)
#pragma unroll
        for (int j = 0; j < 4; ++j) acc[i][j] = fmaf(ar[i], br[j], acc[i][j]);
    }
  }
#pragma unroll
  for (int i = 0; i < 4; ++i) {
    int r = m0 + tm * 4 + i;                 // r = b*128 + t
    long long gb = (long long)((r & 127) * 16 + (r >> 7)) * (3 * NH);  // (t*16+b)*1536
#pragma unroll
    for (int j = 0; j < 4; ++j) {
      int jg = n0 + tn * 4 + j;
      gi_all[gb + jg] = acc[i][j] + b_ih[jg];
    }
  }
}

// ---------------- K3: GRU recurrence. 128 blocks (16 b x 8 sub) x 512 threads ----------------
// Weights in VGPRs. h exchange: single 64-bit word {tag,bits} per (b,h), double-buffered
// by step parity; relaxed agent-scope atomics (payload rides in the atomic -> no fences).
__global__ __launch_bounds__(512, 2) void k_rec(const float* __restrict__ whhT,
                                                const float* __restrict__ gi_all,
                                                const float* __restrict__ b_hh,
                                                float* __restrict__ h_all,
                                                unsigned long long* __restrict__ htag,
                                                float* __restrict__ d_hf) {
  const int tid = threadIdx.x;
  const int b = blockIdx.x & 15, sub = blockIdx.x >> 4;   // same-b blocks share bid%8 -> same-XCD heuristic
  const int hl = tid & 63, kc = tid >> 6;                 // 64 h x 8 k-chunks
  const int j = sub * 64 + hl;
  __shared__ float hbuf[512];
  __shared__ float part[3][8][64];

  // preload weights into registers: wg[g][q] = W^T[kc*64+q][g*512+j]
  float wg[3][64];
#pragma unroll
  for (int g = 0; g < 3; ++g) {
    const float* wp = whhT + (long long)(kc * 64) * 1536 + g * 512 + j;
#pragma unroll
    for (int q = 0; q < 64; ++q) wg[g][q] = wp[(long long)q * 1536];
  }
  float bhr = 0.f, bhz = 0.f, bhn = 0.f;
  if (tid < 64) {
    bhr = b_hh[sub * 64 + tid];
    bhz = b_hh[512 + sub * 64 + tid];
    bhn = b_hh[1024 + sub * 64 + tid];
  }

  for (int t = 0; t < NT; ++t) {
    // prefetch gi (hides HBM latency under the poll+dot)
    float gr = 0.f, gz = 0.f, gn = 0.f;
    if (tid < 64) {
      const float* gi = gi_all + (long long)(t * 16 + b) * 1536;
      gr = gi[sub * 64 + tid];
      gz = gi[512 + sub * 64 + tid];
      gn = gi[1024 + sub * 64 + tid];
    }
    // consume h_t: poll my slot in buffer (t&1) until tag == t+1
    {
      unsigned long long* slot = htag + ((long long)(t & 1) * NB + b) * 512 + tid;
      unsigned long long v = __hip_atomic_load(slot, __ATOMIC_RELAXED, __HIP_MEMORY_SCOPE_AGENT);
      int guard = 0;
      while ((unsigned)(v >> 32) != (unsigned)(t + 1) && ++guard < (1 << 20)) {
        __builtin_amdgcn_s_sleep(1);
        v = __hip_atomic_load(slot, __ATOMIC_RELAXED, __HIP_MEMORY_SCOPE_AGENT);
      }
      union { unsigned u; float f; } c; c.u = (unsigned)v;
      hbuf[tid] = c.f;
    }
    __syncthreads();
    // dot: 192 FMA from registers
    float ar = 0.f, az = 0.f, an = 0.f;
#pragma unroll
    for (int q4 = 0; q4 < 4; ++q4) {
      float4 h4[4];
#pragma unroll
      for (int u = 0; u < 4; ++u) h4[u] = *(const float4*)&hbuf[kc * 64 + q4 * 16 + u * 4];
#pragma unroll
      for (int u = 0; u < 4; ++u) {
        const float hh[4] = {h4[u].x, h4[u].y, h4[u].z, h4[u].w};
#pragma unroll
        for (int v = 0; v < 4; ++v) {
          const int q = q4 * 16 + u * 4 + v;
          ar = fmaf(hh[v], wg[0][q], ar);
          az = fmaf(hh[v], wg[1][q], az);
          an = fmaf(hh[v], wg[2][q], an);
        }
      }
    }
    part[0][kc][hl] = ar; part[1][kc][hl] = az; part[2][kc][hl] = an;
    __syncthreads();
    if (tid < 64) {
      float sr = bhr, sz = bhz, sn = bhn;
#pragma unroll
      for (int c = 0; c < 8; ++c) {
        sr += part[0][c][tid]; sz += part[1][c][tid]; sn += part[2][c][tid];
      }
      float r = 1.f / (1.f + expf(-(gr + sr)));
      float z = 1.f / (1.f + expf(-(gz + sz)));
      float n = tanhf(gn + r * sn);
      float hp = hbuf[sub * 64 + tid];
      float hv = (1.f - z) * n + z * hp;
      // publish h_{t+1} for peers: buffer (t+1)&1, tag t+2
      if (t < NT - 1) {
        union { float f; unsigned u; } c2; c2.f = hv;
        unsigned long long out = ((unsigned long long)(unsigned)(t + 2) << 32) | c2.u;
        __hip_atomic_store(htag + ((long long)((t + 1) & 1) * NB + b) * 512 + sub * 64 + tid, out,
                           __ATOMIC_RELAXED, __HIP_MEMORY_SCOPE_AGENT);
      }
      h_all[(long long)((t + 1) * 16 + b) * 512 + sub * 64 + tid] = hv;  // for downstream kernels
      if (t == NT - 1) d_hf[b * 512 + sub * 64 + tid] = hv;
    }
    __syncthreads();  // hbuf consumed by finalize; safe to overwrite next iter
  }
}

// ---------------- K4: attention per (t,b): scores->softmax->mix ----------------
__global__ __launch_bounds__(256) void k_attn(const float* __restrict__ h_all,
                                              const float* __restrict__ enc,
                                              const int* __restrict__ mask,
                                              float* __restrict__ d_attn,
                                              float* __restrict__ mix) {
  const int g = blockIdx.x;
  const int t = g >> 4, b = g & 15;
  const int tid = threadIdx.x;
  __shared__ float hb[512];
  __shared__ float red[256];
  __shared__ float wb[128];
  __shared__ float smax, ssum;
  const float* hsrc = h_all + (long long)((t + 1) * 16 + b) * 512;
  hb[tid] = hsrc[tid];
  hb[tid + 256] = hsrc[tid + 256];
  __syncthreads();
  const int s = tid & 127, half = tid >> 7;
  const float* erow = enc + (long long)(b * 128 + s) * 512 + half * 256;
  float p = 0.f;
#pragma unroll 8
  for (int k = 0; k < 256; ++k) p = fmaf(hb[half * 256 + k], erow[k], p);
  red[tid] = p;
  __syncthreads();
  float sc = 0.f;
  if (tid < 128) {
    sc = red[tid] + red[tid + 128];
    if (mask[b * 128 + tid] == 0) sc = -1e6f;
    wb[tid] = sc;
  }
  __syncthreads();
  if (tid < 64) {
    float m2 = fmaxf(wb[tid], wb[tid + 64]);
    for (int off = 32; off; off >>= 1) m2 = fmaxf(m2, __shfl_down(m2, off));
    if (tid == 0) smax = m2;
  }
  __syncthreads();
  if (tid < 128) wb[tid] = expf(sc - smax);
  __syncthreads();
  if (tid < 64) {
    float s2 = wb[tid] + wb[tid + 64];
    for (int off = 32; off; off >>= 1) s2 += __shfl_down(s2, off);
    if (tid == 0) ssum = s2;
  }
  __syncthreads();
  float inv = 1.f / ssum;
  if (tid < 128) {
    float w = wb[tid] * inv;
    wb[tid] = w;
    d_attn[(long long)(t * 16 + b) * 128 + tid] = w;
  }
  __syncthreads();
  long long mrow = (long long)(b * 128 + t) * 512;
  for (int hh = tid; hh < 512; hh += 256) {
    float acc = 0.f;
#pragma unroll 8
    for (int s2 = 0; s2 < 128; ++s2) acc = fmaf(wb[s2], enc[(long long)(b * 128 + s2) * 512 + hh], acc);
    mix[mrow + hh] = acc;
  }
}

// ---------------- K5: attended = tanh([h,mix] @ lin_out_w^T) -> bf16 ----------------
__global__ __launch_bounds__(256) void k_att_lin(const float* __restrict__ h_all,
                                                 const float* __restrict__ mix,
                                                 const float* __restrict__ W,
                                                 __bf16* __restrict__ attout) {
  __shared__ float As[16][64];
  __shared__ float Bs[16][64];
  const int tid = threadIdx.x;
  const int n0 = blockIdx.x * 64;   // o (0..511)
  const int m0 = blockIdx.y * 64;   // r (0..2047)
  float acc[4][4] = {};
  const int rl = tid >> 2;
  const int kq = (tid & 3) * 4;
  const int tm = tid & 15, tn = tid >> 4;
  const int r_a = m0 + rl;
  const int b_a = r_a >> 7, t_a = r_a & 127;
  const float* hrow = h_all + (long long)((t_a + 1) * 16 + b_a) * 512;
  const float* mrow = mix + (long long)r_a * 512;
  for (int k0 = 0; k0 < 1024; k0 += 16) {
    __syncthreads();
    float4 av = (k0 < 512) ? *(const float4*)(hrow + k0 + kq)
                           : *(const float4*)(mrow + (k0 - 512) + kq);
    float4 bv = *(const float4*)(W + (long long)(n0 + rl) * 1024 + k0 + kq);
    As[kq + 0][rl] = av.x; As[kq + 1][rl] = av.y; As[kq + 2][rl] = av.z; As[kq + 3][rl] = av.w;
    Bs[kq + 0][rl] = bv.x; Bs[kq + 1][rl] = bv.y; Bs[kq + 2][rl] = bv.z; Bs[kq + 3][rl] = bv.w;
    __syncthreads();
#pragma unroll
    for (int kk = 0; kk < 16; ++kk) {
      float4 a = *(const float4*)&As[kk][tm * 4];
      float4 b = *(const float4*)&Bs[kk][tn * 4];
      float ar[4] = {a.x, a.y, a.z, a.w}, br[4] = {b.x, b.y, b.z, b.w};
#pragma unroll
      for (int i = 0; i < 4; ++i)
#pragma unroll
        for (int j = 0; j < 4; ++j) acc[i][j] = fmaf(ar[i], br[j], acc[i][j]);
    }
  }
#pragma unroll
  for (int i = 0; i < 4; ++i) {
    int r = m0 + tm * 4 + i;
#pragma unroll
    for (int j = 0; j < 4; ++j) {
      int o = n0 + tn * 4 + j;
      attout[(long long)r * 512 + o] = (__bf16)tanhf(acc[i][j]);
    }
  }
}

// ---------------- K6: scores = attended @ out_w^T + out_b  (bf16 MFMA, f32 out) ----------------
__global__ __launch_bounds__(256) void k_out(const __bf16* __restrict__ Abf,
                                             const __bf16* __restrict__ Bbf,
                                             const float* __restrict__ bias,
                                             float* __restrict__ Cout) {
  __shared__ __bf16 Al[128 * 32];
  __shared__ __bf16 Bl[128 * 32];
  const int tid = threadIdx.x;
  const int lane = tid & 63;
  const int wave = tid >> 6;
  const int wm = wave >> 1, wn = wave & 1;
  const int m0 = blockIdx.y * 128, n0 = blockIdx.x * 128;
  f32x4 acc[4][4] = {};
  const int lrow = lane >> 2;        // staging row-in-chunk
  const int lcol = (lane & 3) * 8;   // staging col (elements)
  const int lm = lane & 15, lc = lane >> 4;
  for (int ks = 0; ks < 16; ++ks) {
    const int k0 = ks * 32;
    __syncthreads();
#pragma unroll
    for (int i = 0; i < 2; ++i) {
      int chunk = wave * 2 + i;
      int r = chunk * 16 + lrow;
      const __bf16* ga = Abf + (long long)(m0 + r) * NH + k0 + lcol;
      const __bf16* gb = Bbf + (long long)(n0 + r) * NH + k0 + lcol;
      __builtin_amdgcn_global_load_lds((gu32*)ga, (lu32*)((char*)Al + chunk * 1024), 16, 0, 0);
      __builtin_amdgcn_global_load_lds((gu32*)gb, (lu32*)((char*)Bl + chunk * 1024), 16, 0, 0);
    }
    __syncthreads();
    bf16x8 af[4], bfr[4];
#pragma unroll
    for (int i = 0; i < 4; ++i) af[i] = *(const bf16x8*)&Al[(wm * 64 + i * 16 + lm) * 32 + lc * 8];
#pragma unroll
    for (int j = 0; j < 4; ++j) bfr[j] = *(const bf16x8*)&Bl[(wn * 64 + j * 16 + lm) * 32 + lc * 8];
#pragma unroll
    for (int i = 0; i < 4; ++i)
#pragma unroll
      for (int j = 0; j < 4; ++j)
        acc[i][j] = __builtin_amdgcn_mfma_f32_16x16x32_bf16(af[i], bfr[j], acc[i][j], 0, 0, 0);
  }
#pragma unroll
  for (int j = 0; j < 4; ++j) {
    int c = n0 + wn * 64 + j * 16 + lm;
    float bv = bias[c];
#pragma unroll
    for (int i = 0; i < 4; ++i) {
      int rb = m0 + wm * 64 + i * 16 + lc * 4;
#pragma unroll
      for (int q = 0; q < 4; ++q)
        Cout[(long long)(rb + q) * NV + c] = acc[i][j][q] + bv;
    }
  }
}

// ---------------- launch ----------------
extern "C" void kernel_launch(void* const* d_in, const int* in_sizes, int n_in,
                              void* d_out, int out_size, void* d_ws, size_t ws_size,
                              hipStream_t stream) {
  const int* tv = (const int*)d_in[0];
  const float* dh = (const float*)d_in[1];
  const float* enc = (const float*)d_in[2];
  const int* mask = (const int*)d_in[3];
  const float* emb = (const float*)d_in[4];
  const float* w_ih = (const float*)d_in[5];
  const float* w_hh = (const float*)d_in[6];
  const float* b_ih = (const float*)d_in[7];
  const float* b_hh = (const float*)d_in[8];
  const float* lin_w = (const float*)d_in[9];
  const float* out_w = (const float*)d_in[10];
  const float* out_b = (const float*)d_in[11];
  float* dout = (float*)d_out;   // outputs are float32
  char* ws = (char*)d_ws;
  if (ws_size < WS_NEED) return;

  unsigned long long* htag = (unsigned long long*)(ws + HTAG_OFF);
  float* whhT = (float*)(ws + WHHT_OFF);
  float* gi_all = (float*)(ws + GI_OFF);
  float* h_all = (float*)(ws + HALL_OFF);
  float* mixb = (float*)(ws + MIX_OFF);
  __bf16* attb = (__bf16*)(ws + ATTB_OFF);
  __bf16* owb = (__bf16*)(ws + OWB_OFF);

  float* d_scores = dout;                                  // [B,T,V]
  float* d_hf = dout + (long long)NB * NT * NV;            // [1,B,H]
  float* d_attn = d_hf + NB * NH;                          // [T,B,S]

  k_prep<<<1024, 256, 0, stream>>>(w_hh, dh, out_w, whhT, h_all, owb, htag);
  k_gi<<<dim3(24, 32), 256, 0, stream>>>(tv, emb, w_ih, b_ih, gi_all);
  k_rec<<<128, 512, 0, stream>>>(whhT, gi_all, b_hh, h_all, htag, d_hf);
  k_attn<<<2048, 256, 0, stream>>>(h_all, enc, mask, d_attn, mixb);
  k_att_lin<<<dim3(8, 32), 256, 0, stream>>>(h_all, mixb, lin_w, attb);
  k_out<<<dim3(250, 16), 256, 0, stream>>>(attb, owb, out_b, d_scores);
}

// Round 11
// 557.883 us; speedup vs baseline: 5.6973x; 1.0521x over previous
//
#include <hip/hip_runtime.h>
#include <hip/hip_bf16.h>

#define NV 32000
#define NE 512
#define NH 512
#define NB 16
#define NT 128
#define NS 128

typedef __bf16 bf16x8 __attribute__((ext_vector_type(8)));
typedef float f32x4 __attribute__((ext_vector_type(4)));
typedef const __attribute__((address_space(1))) unsigned int gu32;
typedef __attribute__((address_space(3))) unsigned int lu32;

// ---------------- workspace layout (bytes) ----------------
static constexpr size_t HTAG_OFF = 0;                                     // [2][16][512] u64 = 128 KB
static constexpr size_t WHHT_OFF = HTAG_OFF + (size_t)2*NB*NH*8;          // [512][1536] f32
static constexpr size_t GI_OFF   = WHHT_OFF + (size_t)3*NH*NH*4;          // [T][B][1536] f32
static constexpr size_t HALL_OFF = GI_OFF + (size_t)NT*NB*3*NH*4;         // [T+1][B][512] f32
static constexpr size_t MIX_OFF  = HALL_OFF + (size_t)(NT+1)*NB*NH*4;     // [B*T][512] f32
static constexpr size_t ATTB_OFF = MIX_OFF + (size_t)NB*NT*NH*4;          // [B*T][512] bf16
static constexpr size_t OWB_OFF  = ATTB_OFF + (size_t)NB*NT*NH*2;         // [V][512] bf16
static constexpr size_t WS_NEED  = OWB_OFF + (size_t)NV*NH*2;             // ~59.1 MB

// ---------------- K1: merged prep + gi ----------------
// blocks 0..767: gi = emb(text_vec) @ w_ih^T + b_ih   (24 n-tiles x 32 m-tiles)
// blocks 768..1791: out_w->bf16, whhT transpose, h0/htag seed (1024 virtual blocks)
__global__ __launch_bounds__(256) void k_pg(const int* __restrict__ tv,
                                            const float* __restrict__ emb,
                                            const float* __restrict__ w_ih,
                                            const float* __restrict__ b_ih,
                                            float* __restrict__ gi_all,
                                            const float* __restrict__ w_hh,
                                            const float* __restrict__ dh,
                                            const float* __restrict__ out_w,
                                            float* __restrict__ whhT,
                                            float* __restrict__ h_all,
                                            __bf16* __restrict__ owb,
                                            unsigned long long* __restrict__ htag) {
  const int g = blockIdx.x;
  const int tid = threadIdx.x;
  if (g >= 768) {
    // ---- prep part ----
    long long i0 = (long long)(g - 768) * 256 + tid;
    long long stride = (long long)1024 * 256;
    long long n4 = (long long)NV * NH / 4;
    for (long long i = i0; i < n4; i += stride) {
      float4 v = ((const float4*)out_w)[i];
      union { __bf16 b[4]; float2 f2; } u;
      u.b[0] = (__bf16)v.x; u.b[1] = (__bf16)v.y; u.b[2] = (__bf16)v.z; u.b[3] = (__bf16)v.w;
      *((float2*)(owb + 4 * i)) = u.f2;
    }
    for (long long i = i0; i < (long long)3 * NH * NH; i += stride) {
      int k = (int)(i / (3 * NH)), j = (int)(i % (3 * NH));
      whhT[i] = w_hh[(long long)j * NH + k];
    }
    for (long long i = i0; i < NB * NH; i += stride) {
      float hv = dh[i];
      h_all[i] = hv;
      union { float f; unsigned u; } c; c.f = hv;
      htag[i] = (1ull << 32) | c.u;
      htag[NB * NH + i] = 0ull;
    }
    return;
  }
  // ---- gi part ----
  __shared__ float As[16][64];
  __shared__ float Bs[16][64];
  const int n0 = (g % 24) * 64;   // j (0..1535)
  const int m0 = (g / 24) * 64;   // bt row (0..2047)
  float acc[4][4] = {};
  const int rl = tid >> 2;        // 0..63
  const int kq = (tid & 3) * 4;   // 0,4,8,12
  const int tvr = tv[m0 + rl];
  const float* arow = emb + (long long)tvr * NE;
  const int tm = tid & 15, tn = tid >> 4;
  for (int k0 = 0; k0 < NE; k0 += 16) {
    __syncthreads();
    float4 av = make_float4(0.f, 0.f, 0.f, 0.f);
    if (tvr != 0) av = *(const float4*)(arow + k0 + kq);
    float4 bv = *(const float4*)(w_ih + (long long)(n0 + rl) * NE + k0 + kq);
    As[kq + 0][rl] = av.x; As[kq + 1][rl] = av.y; As[kq + 2][rl] = av.z; As[kq + 3][rl] = av.w;
    Bs[kq + 0][rl] = bv.x; Bs[kq + 1][rl] = bv.y; Bs[kq + 2][rl] = bv.z; Bs[kq + 3][rl] = bv.w;
    __syncthreads();
#pragma unroll
    for (int kk = 0; kk < 16; ++kk) {
      float4 a = *(const float4*)&As[kk][tm * 4];
      float4 b = *(const float4*)&Bs[kk][tn * 4];
      float ar[4] = {a.x, a.y, a.z, a.w}, br[4] = {b.x, b.y, b.z, b.w};
#pragma unroll
      for (int i = 0; i < 4; ++i)
#pragma unroll
        for (int j = 0; j < 4; ++j) acc[i][j] = fmaf(ar[i], br[j], acc[i][j]);
    }
  }
#pragma unroll
  for (int i = 0; i < 4; ++i) {
    int r = m0 + tm * 4 + i;                 // r = b*128 + t
    long long gb = (long long)((r & 127) * 16 + (r >> 7)) * (3 * NH);  // (t*16+b)*1536
#pragma unroll
    for (int j = 0; j < 4; ++j) {
      int jg = n0 + tn * 4 + j;
      gi_all[gb + jg] = acc[i][j] + b_ih[jg];
    }
  }
}

// ---------------- K3: GRU recurrence. 128 blocks (16 b x 8 sub) x 512 threads ----------------
__global__ __launch_bounds__(512, 2) void k_rec(const float* __restrict__ whhT,
                                                const float* __restrict__ gi_all,
                                                const float* __restrict__ b_hh,
                                                float* __restrict__ h_all,
                                                unsigned long long* __restrict__ htag,
                                                float* __restrict__ d_hf) {
  const int tid = threadIdx.x;
  const int b = blockIdx.x & 15, sub = blockIdx.x >> 4;   // same-b blocks share bid%8 -> same-XCD heuristic
  const int hl = tid & 63, kc = tid >> 6;                 // 64 h x 8 k-chunks
  const int j = sub * 64 + hl;
  __shared__ float hbuf[512];
  __shared__ float part[3][8][64];

  float wg[3][64];
#pragma unroll
  for (int g = 0; g < 3; ++g) {
    const float* wp = whhT + (long long)(kc * 64) * 1536 + g * 512 + j;
#pragma unroll
    for (int q = 0; q < 64; ++q) wg[g][q] = wp[(long long)q * 1536];
  }
  float bhr = 0.f, bhz = 0.f, bhn = 0.f;
  if (tid < 64) {
    bhr = b_hh[sub * 64 + tid];
    bhz = b_hh[512 + sub * 64 + tid];
    bhn = b_hh[1024 + sub * 64 + tid];
  }

  for (int t = 0; t < NT; ++t) {
    float gr = 0.f, gz = 0.f, gn = 0.f;
    if (tid < 64) {
      const float* gi = gi_all + (long long)(t * 16 + b) * 1536;
      gr = gi[sub * 64 + tid];
      gz = gi[512 + sub * 64 + tid];
      gn = gi[1024 + sub * 64 + tid];
    }
    // consume h_t: poll my slot in buffer (t&1) until tag == t+1 (tight spin; payload in atomic)
    {
      unsigned long long* slot = htag + ((long long)(t & 1) * NB + b) * 512 + tid;
      unsigned long long v = __hip_atomic_load(slot, __ATOMIC_RELAXED, __HIP_MEMORY_SCOPE_AGENT);
      int guard = 0;
      while ((unsigned)(v >> 32) != (unsigned)(t + 1) && ++guard < (1 << 22)) {
        v = __hip_atomic_load(slot, __ATOMIC_RELAXED, __HIP_MEMORY_SCOPE_AGENT);
      }
      union { unsigned u; float f; } c; c.u = (unsigned)v;
      hbuf[tid] = c.f;
    }
    __syncthreads();
    float ar = 0.f, az = 0.f, an = 0.f;
#pragma unroll
    for (int q4 = 0; q4 < 4; ++q4) {
      float4 h4[4];
#pragma unroll
      for (int u = 0; u < 4; ++u) h4[u] = *(const float4*)&hbuf[kc * 64 + q4 * 16 + u * 4];
#pragma unroll
      for (int u = 0; u < 4; ++u) {
        const float hh[4] = {h4[u].x, h4[u].y, h4[u].z, h4[u].w};
#pragma unroll
        for (int v = 0; v < 4; ++v) {
          const int q = q4 * 16 + u * 4 + v;
          ar = fmaf(hh[v], wg[0][q], ar);
          az = fmaf(hh[v], wg[1][q], az);
          an = fmaf(hh[v], wg[2][q], an);
        }
      }
    }
    part[0][kc][hl] = ar; part[1][kc][hl] = az; part[2][kc][hl] = an;
    __syncthreads();
    if (tid < 64) {
      float sr = bhr, sz = bhz, sn = bhn;
#pragma unroll
      for (int c = 0; c < 8; ++c) {
        sr += part[0][c][tid]; sz += part[1][c][tid]; sn += part[2][c][tid];
      }
      float r = 1.f / (1.f + expf(-(gr + sr)));
      float z = 1.f / (1.f + expf(-(gz + sz)));
      float n = tanhf(gn + r * sn);
      float hp = hbuf[sub * 64 + tid];
      float hv = (1.f - z) * n + z * hp;
      if (t < NT - 1) {
        union { float f; unsigned u; } c2; c2.f = hv;
        unsigned long long out = ((unsigned long long)(unsigned)(t + 2) << 32) | c2.u;
        __hip_atomic_store(htag + ((long long)((t + 1) & 1) * NB + b) * 512 + sub * 64 + tid, out,
                           __ATOMIC_RELAXED, __HIP_MEMORY_SCOPE_AGENT);
      }
      h_all[(long long)((t + 1) * 16 + b) * 512 + sub * 64 + tid] = hv;
      if (t == NT - 1) d_hf[b * 512 + sub * 64 + tid] = hv;
    }
    __syncthreads();
  }
}

// ---------------- K4: attention per (t,b): scores->softmax->mix ----------------
__global__ __launch_bounds__(256) void k_attn(const float* __restrict__ h_all,
                                              const float* __restrict__ enc,
                                              const int* __restrict__ mask,
                                              float* __restrict__ d_attn,
                                              float* __restrict__ mix) {
  const int g = blockIdx.x;
  const int t = g >> 4, b = g & 15;
  const int tid = threadIdx.x;
  __shared__ float hb[512];
  __shared__ float red[256];
  __shared__ float wb[128];
  __shared__ float smax, ssum;
  const float* hsrc = h_all + (long long)((t + 1) * 16 + b) * 512;
  hb[tid] = hsrc[tid];
  hb[tid + 256] = hsrc[tid + 256];
  __syncthreads();
  const int s = tid & 127, half = tid >> 7;
  const float* erow = enc + (long long)(b * 128 + s) * 512 + half * 256;
  float p = 0.f;
#pragma unroll 8
  for (int k = 0; k < 256; ++k) p = fmaf(hb[half * 256 + k], erow[k], p);
  red[tid] = p;
  __syncthreads();
  float sc = 0.f;
  if (tid < 128) {
    sc = red[tid] + red[tid + 128];
    if (mask[b * 128 + tid] == 0) sc = -1e6f;
    wb[tid] = sc;
  }
  __syncthreads();
  if (tid < 64) {
    float m2 = fmaxf(wb[tid], wb[tid + 64]);
    for (int off = 32; off; off >>= 1) m2 = fmaxf(m2, __shfl_down(m2, off));
    if (tid == 0) smax = m2;
  }
  __syncthreads();
  if (tid < 128) wb[tid] = expf(sc - smax);
  __syncthreads();
  if (tid < 64) {
    float s2 = wb[tid] + wb[tid + 64];
    for (int off = 32; off; off >>= 1) s2 += __shfl_down(s2, off);
    if (tid == 0) ssum = s2;
  }
  __syncthreads();
  float inv = 1.f / ssum;
  if (tid < 128) {
    float w = wb[tid] * inv;
    wb[tid] = w;
    d_attn[(long long)(t * 16 + b) * 128 + tid] = w;
  }
  __syncthreads();
  long long mrow = (long long)(b * 128 + t) * 512;
  for (int hh = tid; hh < 512; hh += 256) {
    float acc = 0.f;
#pragma unroll 8
    for (int s2 = 0; s2 < 128; ++s2) acc = fmaf(wb[s2], enc[(long long)(b * 128 + s2) * 512 + hh], acc);
    mix[mrow + hh] = acc;
  }
}

// ---------------- K5: attended = tanh([h,mix] @ lin_out_w^T) -> bf16 ----------------
__global__ __launch_bounds__(256) void k_att_lin(const float* __restrict__ h_all,
                                                 const float* __restrict__ mix,
                                                 const float* __restrict__ W,
                                                 __bf16* __restrict__ attout) {
  __shared__ float As[16][64];
  __shared__ float Bs[16][64];
  const int tid = threadIdx.x;
  const int n0 = blockIdx.x * 64;   // o (0..511)
  const int m0 = blockIdx.y * 64;   // r (0..2047)
  float acc[4][4] = {};
  const int rl = tid >> 2;
  const int kq = (tid & 3) * 4;
  const int tm = tid & 15, tn = tid >> 4;
  const int r_a = m0 + rl;
  const int b_a = r_a >> 7, t_a = r_a & 127;
  const float* hrow = h_all + (long long)((t_a + 1) * 16 + b_a) * 512;
  const float* mrow = mix + (long long)r_a * 512;
  for (int k0 = 0; k0 < 1024; k0 += 16) {
    __syncthreads();
    float4 av = (k0 < 512) ? *(const float4*)(hrow + k0 + kq)
                           : *(const float4*)(mrow + (k0 - 512) + kq);
    float4 bv = *(const float4*)(W + (long long)(n0 + rl) * 1024 + k0 + kq);
    As[kq + 0][rl] = av.x; As[kq + 1][rl] = av.y; As[kq + 2][rl] = av.z; As[kq + 3][rl] = av.w;
    Bs[kq + 0][rl] = bv.x; Bs[kq + 1][rl] = bv.y; Bs[kq + 2][rl] = bv.z; Bs[kq + 3][rl] = bv.w;
    __syncthreads();
#pragma unroll
    for (int kk = 0; kk < 16; ++kk) {
      float4 a = *(const float4*)&As[kk][tm * 4];
      float4 b = *(const float4*)&Bs[kk][tn * 4];
      float ar[4] = {a.x, a.y, a.z, a.w}, br[4] = {b.x, b.y, b.z, b.w};
#pragma unroll
      for (int i = 0; i < 4; ++i)
#pragma unroll
        for (int j = 0; j < 4; ++j) acc[i][j] = fmaf(ar[i], br[j], acc[i][j]);
    }
  }
#pragma unroll
  for (int i = 0; i < 4; ++i) {
    int r = m0 + tm * 4 + i;
#pragma unroll
    for (int j = 0; j < 4; ++j) {
      int o = n0 + tn * 4 + j;
      attout[(long long)r * 512 + o] = (__bf16)tanhf(acc[i][j]);
    }
  }
}

// ---------------- K6: scores = attended @ out_w^T + out_b  (bf16 MFMA, f32 out) ----------------
// 1D grid 4000; bijective XCD swizzle so all 16 m-tiles of an owb n-tile share one XCD's L2.
__global__ __launch_bounds__(256) void k_out(const __bf16* __restrict__ Abf,
                                             const __bf16* __restrict__ Bbf,
                                             const float* __restrict__ bias,
                                             float* __restrict__ Cout) {
  __shared__ __bf16 Al[128 * 32];
  __shared__ __bf16 Bl[128 * 32];
  const int tid = threadIdx.x;
  const int lane = tid & 63;
  const int wave = tid >> 6;
  const int wm = wave >> 1, wn = wave & 1;
  const int swz = (blockIdx.x & 7) * 500 + (blockIdx.x >> 3);  // 4000 % 8 == 0 -> bijective
  const int m0 = (swz & 15) * 128, n0 = (swz >> 4) * 128;
  f32x4 acc[4][4] = {};
  const int lrow = lane >> 2;
  const int lcol = (lane & 3) * 8;
  const int lm = lane & 15, lc = lane >> 4;
  for (int ks = 0; ks < 16; ++ks) {
    const int k0 = ks * 32;
    __syncthreads();
#pragma unroll
    for (int i = 0; i < 2; ++i) {
      int chunk = wave * 2 + i;
      int r = chunk * 16 + lrow;
      const __bf16* ga = Abf + (long long)(m0 + r) * NH + k0 + lcol;
      const __bf16* gb = Bbf + (long long)(n0 + r) * NH + k0 + lcol;
      __builtin_amdgcn_global_load_lds((gu32*)ga, (lu32*)((char*)Al + chunk * 1024), 16, 0, 0);
      __builtin_amdgcn_global_load_lds((gu32*)gb, (lu32*)((char*)Bl + chunk * 1024), 16, 0, 0);
    }
    __syncthreads();
    bf16x8 af[4], bfr[4];
#pragma unroll
    for (int i = 0; i < 4; ++i) af[i] = *(const bf16x8*)&Al[(wm * 64 + i * 16 + lm) * 32 + lc * 8];
#pragma unroll
    for (int j = 0; j < 4; ++j) bfr[j] = *(const bf16x8*)&Bl[(wn * 64 + j * 16 + lm) * 32 + lc * 8];
#pragma unroll
    for (int i = 0; i < 4; ++i)
#pragma unroll
      for (int j = 0; j < 4; ++j)
        acc[i][j] = __builtin_amdgcn_mfma_f32_16x16x32_bf16(af[i], bfr[j], acc[i][j], 0, 0, 0);
  }
#pragma unroll
  for (int j = 0; j < 4; ++j) {
    int c = n0 + wn * 64 + j * 16 + lm;
    float bv = bias[c];
#pragma unroll
    for (int i = 0; i < 4; ++i) {
      int rb = m0 + wm * 64 + i * 16 + lc * 4;
#pragma unroll
      for (int q = 0; q < 4; ++q)
        Cout[(long long)(rb + q) * NV + c] = acc[i][j][q] + bv;
    }
  }
}

// ---------------- launch ----------------
extern "C" void kernel_launch(void* const* d_in, const int* in_sizes, int n_in,
                              void* d_out, int out_size, void* d_ws, size_t ws_size,
                              hipStream_t stream) {
  const int* tv = (const int*)d_in[0];
  const float* dh = (const float*)d_in[1];
  const float* enc = (const float*)d_in[2];
  const int* mask = (const int*)d_in[3];
  const float* emb = (const float*)d_in[4];
  const float* w_ih = (const float*)d_in[5];
  const float* w_hh = (const float*)d_in[6];
  const float* b_ih = (const float*)d_in[7];
  const float* b_hh = (const float*)d_in[8];
  const float* lin_w = (const float*)d_in[9];
  const float* out_w = (const float*)d_in[10];
  const float* out_b = (const float*)d_in[11];
  float* dout = (float*)d_out;   // outputs are float32
  char* ws = (char*)d_ws;
  if (ws_size < WS_NEED) return;

  unsigned long long* htag = (unsigned long long*)(ws + HTAG_OFF);
  float* whhT = (float*)(ws + WHHT_OFF);
  float* gi_all = (float*)(ws + GI_OFF);
  float* h_all = (float*)(ws + HALL_OFF);
  float* mixb = (float*)(ws + MIX_OFF);
  __bf16* attb = (__bf16*)(ws + ATTB_OFF);
  __bf16* owb = (__bf16*)(ws + OWB_OFF);

  float* d_scores = dout;                                  // [B,T,V]
  float* d_hf = dout + (long long)NB * NT * NV;            // [1,B,H]
  float* d_attn = d_hf + NB * NH;                          // [T,B,S]

  k_pg<<<1792, 256, 0, stream>>>(tv, emb, w_ih, b_ih, gi_all,
                                 w_hh, dh, out_w, whhT, h_all, owb, htag);
  k_rec<<<128, 512, 0, stream>>>(whhT, gi_all, b_hh, h_all, htag, d_hf);
  k_attn<<<2048, 256, 0, stream>>>(h_all, enc, mask, d_attn, mixb);
  k_att_lin<<<dim3(8, 32), 256, 0, stream>>>(h_all, mixb, lin_w, attb);
  k_out<<<4000, 256, 0, stream>>>(attb, owb, out_b, d_scores);
}